// Round 7
// baseline (456.865 us; speedup 1.0000x reference)
//
#include <hip/hip_runtime.h>

#define D_IN_   50937
#define D_LYR_  50425
#define NCH     24
#define NBE     16
#define NME     128
#define NOUT    168
#define NPAD    192
#define KROWS   50688        // padded GEMM K: 256 melody + 50432 lyrics (mult of 64)
#define KSPLIT  16
#define TOTSTEP 792          // KROWS/64
#define PARTN   (2048*168)   // 344064

typedef __attribute__((ext_vector_type(8))) short short8;
typedef __attribute__((ext_vector_type(4))) float f32x4;
typedef float f32x4u __attribute__((ext_vector_type(4), aligned(4)));
typedef __attribute__((ext_vector_type(2))) unsigned int u32x2;

static __device__ __forceinline__ unsigned short f2bf(float f) {
    unsigned int u = __float_as_uint(f);
    u += 0x7FFF + ((u >> 16) & 1);          // round-to-nearest-even
    return (unsigned short)(u >> 16);
}
static __device__ __forceinline__ unsigned int pack2(float x, float y) {
    return (unsigned int)f2bf(x) | ((unsigned int)f2bf(y) << 16);
}

// scalar W[d][n] over concatenated heads
static __device__ __forceinline__ float wsrc(const float* wc, const float* wb,
                                             const float* wm, int d, int n) {
    if (n < NCH)        return wc[d * NCH + n];
    if (n < NCH + NBE)  return wb[d * NBE + (n - NCH)];
    if (n < NOUT)       return wm[(long)d * NME + (n - NCH - NBE)];
    return 0.f;
}
// quad W[d][n0..n0+3]; head boundaries (24,40,168) are 4-aligned so quads never straddle
static __device__ __forceinline__ f32x4 wsrc4(const float* wc, const float* wb,
                                              const float* wm, int d, int nq) {
    int n0 = nq * 4;
    if (n0 < 24)  return *(const f32x4*)(wc + d * 24 + n0);
    if (n0 < 40)  return *(const f32x4*)(wb + d * 16 + (n0 - 24));
    if (n0 < 168) return *(const f32x4*)(wm + (long)d * 128 + (n0 - 40));
    f32x4 z = {0.f, 0.f, 0.f, 0.f};
    return z;
}

// folded, transposed, bf16 weights: wbt[n][r], r = d-256
__global__ __launch_bounds__(256) void k_fold(const float* wc, const float* wb,
                                              const float* wm_, const float* conv_w,
                                              unsigned short* wbt) {
    __shared__ unsigned short tile[64 * 196];   // [dloc][n], pad 196 (8B-aligned rows)
    float cw0 = conv_w[3], cw1 = conv_w[4], cw2 = conv_w[5];
    int r0 = blockIdx.x * 64;
    int tid = threadIdx.x;
    for (int i = 0; i < 12; ++i) {
        int idx = tid + i * 256;                // 64 rows x 48 quads
        int dl = idx / 48, nq = idx % 48;
        int r = r0 + dl;
        f32x4 v = {0.f, 0.f, 0.f, 0.f};
        if (r < 50681) {                        // rows >= 50681 stay zero (pads A-tail)
            int d = 256 + r;
            f32x4 w0 = wsrc4(wc, wb, wm_, d, nq);
            f32x4 wn1 = wsrc4(wc, wb, wm_, d - 1, nq);
            v = cw1 * w0 + cw2 * wn1;
            if (d + 1 < D_IN_) v += cw0 * wsrc4(wc, wb, wm_, d + 1, nq);
        }
        u32x2 p; p.x = pack2(v.x, v.y); p.y = pack2(v.z, v.w);
        *(u32x2*)&tile[dl * 196 + nq * 4] = p;
    }
    __syncthreads();
    for (int i = 0; i < 6; ++i) {
        int idx = tid + i * 256;                // 192 n x 8 chunks
        int n = idx >> 3, ch = idx & 7;
        short8 o;
        for (int j = 0; j < 8; ++j) o[j] = (short)tile[(ch * 8 + j) * 196 + n];
        *(short8*)(wbt + (long)n * KROWS + r0 + ch * 8) = o;
    }
}

// C[j] = bias + ctx @ W'[0:256, j] (+ conv_b * colsum, generally zero); ctx fused in
__global__ void k_cvec(const int* genre, const int* tempo, const int* keysig,
                       const float* emb,
                       const float* wc, const float* wb, const float* wm_,
                       const float* conv_w, const float* conv_b,
                       const float* bc, const float* bb, const float* bm_, float* C) {
    int j = blockIdx.x;          // 0..167
    int lane = threadIdx.x;      // 64
    int g = genre[0], tt = tempo[0], kk = keysig[0];
    float cw0 = conv_w[3], cw1 = conv_w[4], cw2 = conv_w[5];
    float s = 0.f;
    for (int d = lane; d < 256; d += 64) {
        float cx = emb[g * 256 + d] + emb[(10 + tt) * 256 + d] +
                   emb[(20 + kk) * 256 + d] + emb[34 * 256 + d];
        float wp = cw1 * wsrc(wc, wb, wm_, d, j) + cw0 * wsrc(wc, wb, wm_, d + 1, j);
        if (d > 0) wp += cw2 * wsrc(wc, wb, wm_, d - 1, j);
        s += cx * wp;
    }
    float cb = conv_b[0];
    if (cb != 0.f) {
        float cs = 0.f;
        for (int d = lane; d < D_IN_; d += 64) cs += wsrc(wc, wb, wm_, d, j);
        s += cb * cs;
    }
    for (int off = 32; off; off >>= 1) s += __shfl_down(s, off);
    if (lane == 0) {
        float b = (j < NCH) ? bc[j] : (j < NCH + NBE) ? bb[j - NCH] : bm_[j - NCH - NBE];
        C[j] = s + b;
    }
}

// Split-K GEMM (R2 skeleton, evolved):
//  - B: reg-staged LDS double-buffer (R2-verified layout/swizzle): load B(t+1) to
//    regs at phase start, ds_write to buf^1 after compute, lgkm-only barrier.
//  - A: direct global->reg fragments, 2-ahead, 3 named regsets (modulo-3).
//  - Barrier = s_waitcnt lgkmcnt(0) + raw s_barrier: NO vmcnt drain, so A-loads
//    (and nothing else pending) stay in flight across barriers. Correctness:
//    B regs are consumed by ds_write pre-barrier (vmcnt auto-forced); A regs are
//    wave-private dataflow (compiler-inserted vmcnt at the pack); LDS WAR/RAW
//    ordered by lgkmcnt(0)+barrier.
__global__ __launch_bounds__(512, 4) void k_gemm(const float* mel, const float* lyr,
                                                 const unsigned short* wbt,
                                                 float* partial) {
    __shared__ unsigned short Bs[2 * NPAD * 64];   // 2 x 24 KB
    const int blk = blockIdx.x;
    const int ks = ((blk & 7) << 1) | ((blk >> 3) & 1);  // XCD x -> ks {2x,2x+1}
    const int bm = blk >> 4;                             // 0..31 (64-row tiles)
    const int tid = threadIdx.x, lane = tid & 63, wv = tid >> 6;
    const int wm = wv >> 1, wn = wv & 1;                 // 4 M-groups x 2 N-groups
    const int l15 = lane & 15, lk = lane >> 4;
    const int start = ks * 49 + (ks < 8 ? ks : 8);
    const int cnt = 49 + (ks < 8 ? 1 : 0);

    const int arow = bm * 64 + wm * 16 + l15;
    const float* melB = mel + arow * 256;
    const float* lyrB = lyr + (long)arow * D_LYR_ - 256;   // +r gives lyric col

    const int bn = tid >> 3, bch = tid & 7;        // B-stage coords (3 rows/thread)

    f32x4 acc[6];
    #pragma unroll
    for (int i = 0; i < 6; ++i) acc[i] = (f32x4){0.f, 0.f, 0.f, 0.f};

    auto loadBreg = [&](int t2, short8* brg) {     // 3 x 16B per thread, L2-resident
        int r0 = (start + t2) * 64;
        #pragma unroll
        for (int i = 0; i < 3; ++i) {
            int n = bn + i * 64;
            brg[i] = *(const short8*)(wbt + (long)n * KROWS + r0 + bch * 8);
        }
    };
    auto writeB = [&](const short8* brg, int buf) {
        char* Bb = (char*)Bs + buf * 24576;
        #pragma unroll
        for (int i = 0; i < 3; ++i) {
            int n = bn + i * 64;
            *(short8*)(Bb + n * 128 + ((bch * 16) ^ ((n & 7) << 4))) = brg[i];
        }
    };

    auto loadA = [&](int t2, f32x4* dst) {         // dst[4] = [kk*2 + half]
        int gt = start + t2;
        int r0 = gt * 64;
        if (gt != TOTSTEP - 1) {                   // uniform fast path
            #pragma unroll
            for (int kk = 0; kk < 2; ++kk) {
                int r = r0 + kk * 32 + lk * 8;
                const float* p = (r < 256) ? (melB + r) : (lyrB + r);
                dst[kk * 2]     = *(const f32x4u*)p;
                dst[kk * 2 + 1] = *(const f32x4u*)(p + 4);
            }
        } else {                                   // tail tile (block-uniform branch)
            #pragma unroll
            for (int kk = 0; kk < 2; ++kk) {
                int r = r0 + kk * 32 + lk * 8;
                const float* p = lyrB + r;
                int c = r - 256;
                f32x4 v0, v1;
                #pragma unroll
                for (int q = 0; q < 4; ++q) {
                    v0[q] = (c + q     < D_LYR_) ? p[q]     : 0.f;
                    v1[q] = (c + 4 + q < D_LYR_) ? p[4 + q] : 0.f;
                }
                dst[kk * 2] = v0; dst[kk * 2 + 1] = v1;
            }
        }
    };

    auto compute = [&](const f32x4* a, int buf) {
        const char* Bb = (const char*)Bs + buf * 24576;
        #pragma unroll
        for (int kk = 0; kk < 2; ++kk) {
            f32x4 v0 = a[kk * 2], v1 = a[kk * 2 + 1];
            short8 af;
            af[0] = (short)f2bf(v0.x); af[1] = (short)f2bf(v0.y);
            af[2] = (short)f2bf(v0.z); af[3] = (short)f2bf(v0.w);
            af[4] = (short)f2bf(v1.x); af[5] = (short)f2bf(v1.y);
            af[6] = (short)f2bf(v1.z); af[7] = (short)f2bf(v1.w);
            #pragma unroll
            for (int ni = 0; ni < 6; ++ni) {
                int n = wn * 96 + ni * 16 + l15;
                int byte = n * 128 + (((kk * 64) + lk * 16) ^ ((n & 7) << 4));
                short8 bf = *(const short8*)(Bb + byte);
                acc[ni] = __builtin_amdgcn_mfma_f32_16x16x32_bf16(af, bf, acc[ni], 0, 0, 0);
            }
        }
    };

    f32x4 rg0[4], rg1[4], rg2[4];
    // prologue: A(0), A(1) issued (stay in flight across barrier); B(0) -> buf0
    loadA(0, rg0);
    loadA(1, rg1);
    {
        short8 b0[3];
        loadBreg(0, b0);
        writeB(b0, 0);
    }
    asm volatile("s_waitcnt lgkmcnt(0)" ::: "memory");
    __builtin_amdgcn_s_barrier();
    __builtin_amdgcn_sched_barrier(0);

    // phase t: compute A-regs rg[t%3] vs LDS buf[t&1];
    //          prefetch A(t+2) -> rg[(t+2)%3], B(t+1) -> regs -> buf[t&1 ^ 1].
#define PHASE(RGCUR, RGNXT, CURBUF)                                     \
    {                                                                   \
        if (t + 2 < cnt) loadA(t + 2, RGNXT);                           \
        bool pfB = (t + 1 < cnt);                                       \
        short8 brg[3];                                                  \
        if (pfB) loadBreg(t + 1, brg);                                  \
        compute(RGCUR, CURBUF);                                         \
        if (!pfB) break;                                                \
        writeB(brg, CURBUF ^ 1);                                        \
        asm volatile("s_waitcnt lgkmcnt(0)" ::: "memory");              \
        __builtin_amdgcn_s_barrier();                                   \
        __builtin_amdgcn_sched_barrier(0);                              \
        ++t;                                                            \
    }

    int t = 0;
    while (true) {           // period lcm(3 regsets, 2 buffers) = 6
        PHASE(rg0, rg2, 0)
        PHASE(rg1, rg0, 1)
        PHASE(rg2, rg1, 0)
        PHASE(rg0, rg2, 1)
        PHASE(rg1, rg0, 0)
        PHASE(rg2, rg1, 1)
    }
#undef PHASE

    // deterministic partial store
    float* pbase = partial + (long)ks * PARTN;
    int rb = bm * 64 + wm * 16 + lk * 4;
    #pragma unroll
    for (int ni = 0; ni < 6; ++ni) {
        int col = wn * 96 + ni * 16 + l15;
        if (col < NOUT) {
            #pragma unroll
            for (int q = 0; q < 4; ++q)
                pbase[(long)(rb + q) * NOUT + col] = acc[ni][q];
        }
    }
}

__global__ void k_reduce(const float* partial, const float* C, float* out) {
    int idx = blockIdx.x * 256 + threadIdx.x;    // vec4 index
    if (idx >= PARTN / 4) return;
    int base = idx * 4;
    f32x4 s;
    for (int q = 0; q < 4; ++q) s[q] = C[(base + q) % NOUT];
    for (int ks = 0; ks < KSPLIT; ++ks)
        s += *(const f32x4*)(partial + (long)ks * PARTN + base);
    *(f32x4*)(out + base) = s;
}

extern "C" void kernel_launch(void* const* d_in, const int* in_sizes, int n_in,
                              void* d_out, int out_size, void* d_ws, size_t ws_size,
                              hipStream_t stream) {
    const int*   genre   = (const int*)d_in[0];
    const int*   tempo   = (const int*)d_in[1];
    const int*   keysig  = (const int*)d_in[2];
    const float* mel     = (const float*)d_in[4];
    const float* lyr     = (const float*)d_in[5];
    const float* emb     = (const float*)d_in[6];
    const float* conv_w  = (const float*)d_in[7];
    const float* conv_b  = (const float*)d_in[8];
    const float* w_chord = (const float*)d_in[9];
    const float* b_chord = (const float*)d_in[10];
    const float* w_beat  = (const float*)d_in[11];
    const float* b_beat  = (const float*)d_in[12];
    const float* w_mel   = (const float*)d_in[13];
    const float* b_mel   = (const float*)d_in[14];

    char* ws = (char*)d_ws;
    unsigned short* wbt = (unsigned short*)ws;              // 192*50688*2 = 19,464,192 B
    float* Cvec    = (float*)(ws + 19464192);               // 1 KB
    float* partial = (float*)(ws + 19466240);               // 16*344064*4 = 22,020,096 B
    float* out     = (float*)d_out;

    hipLaunchKernelGGL(k_fold, dim3(TOTSTEP), dim3(256), 0, stream,
                       w_chord, w_beat, w_mel, conv_w, wbt);
    hipLaunchKernelGGL(k_cvec, dim3(NOUT), dim3(64), 0, stream,
                       genre, tempo, keysig, emb,
                       w_chord, w_beat, w_mel, conv_w, conv_b,
                       b_chord, b_beat, b_mel, Cvec);
    hipLaunchKernelGGL(k_gemm, dim3(512), dim3(512), 0, stream,
                       mel, lyr, wbt, partial);
    hipLaunchKernelGGL(k_reduce, dim3((PARTN / 4 + 255) / 256), dim3(256), 0, stream,
                       partial, Cvec, out);
}

// Round 8
// 223.721 us; speedup vs baseline: 2.0421x; 2.0421x over previous
//
#include <hip/hip_runtime.h>

#define D_IN_   50937
#define D_LYR_  50425
#define NCH     24
#define NBE     16
#define NME     128
#define NOUT    168
#define NPAD    192
#define KROWS   50688        // padded GEMM K: 256 melody + 50432 lyrics (mult of 64)
#define KSPLIT  16
#define TOTSTEP 792          // KROWS/64
#define PARTN   (2048*168)   // 344064

typedef __attribute__((ext_vector_type(8))) short short8;
typedef __attribute__((ext_vector_type(4))) float f32x4;
typedef float f32x4u __attribute__((ext_vector_type(4), aligned(4)));
typedef __attribute__((ext_vector_type(2))) unsigned int u32x2;

static __device__ __forceinline__ unsigned short f2bf(float f) {
    unsigned int u = __float_as_uint(f);
    u += 0x7FFF + ((u >> 16) & 1);          // round-to-nearest-even
    return (unsigned short)(u >> 16);
}
static __device__ __forceinline__ unsigned int pack2(float x, float y) {
    return (unsigned int)f2bf(x) | ((unsigned int)f2bf(y) << 16);
}

// scalar W[d][n] over concatenated heads
static __device__ __forceinline__ float wsrc(const float* wc, const float* wb,
                                             const float* wm, int d, int n) {
    if (n < NCH)        return wc[d * NCH + n];
    if (n < NCH + NBE)  return wb[d * NBE + (n - NCH)];
    if (n < NOUT)       return wm[(long)d * NME + (n - NCH - NBE)];
    return 0.f;
}
// quad W[d][n0..n0+3]; head boundaries (24,40,168) are 4-aligned so quads never straddle
static __device__ __forceinline__ f32x4 wsrc4(const float* wc, const float* wb,
                                              const float* wm, int d, int nq) {
    int n0 = nq * 4;
    if (n0 < 24)  return *(const f32x4*)(wc + d * 24 + n0);
    if (n0 < 40)  return *(const f32x4*)(wb + d * 16 + (n0 - 24));
    if (n0 < 168) return *(const f32x4*)(wm + (long)d * 128 + (n0 - 40));
    f32x4 z = {0.f, 0.f, 0.f, 0.f};
    return z;
}

// folded, transposed, bf16 weights: wbt[n][r], r = d-256
__global__ __launch_bounds__(256) void k_fold(const float* wc, const float* wb,
                                              const float* wm_, const float* conv_w,
                                              unsigned short* wbt) {
    __shared__ unsigned short tile[64 * 196];   // [dloc][n], pad 196 (8B-aligned rows)
    float cw0 = conv_w[3], cw1 = conv_w[4], cw2 = conv_w[5];
    int r0 = blockIdx.x * 64;
    int tid = threadIdx.x;
    for (int i = 0; i < 12; ++i) {
        int idx = tid + i * 256;                // 64 rows x 48 quads
        int dl = idx / 48, nq = idx % 48;
        int r = r0 + dl;
        f32x4 v = {0.f, 0.f, 0.f, 0.f};
        if (r < 50681) {                        // rows >= 50681 stay zero (pads A-tail)
            int d = 256 + r;
            f32x4 w0 = wsrc4(wc, wb, wm_, d, nq);
            f32x4 wn1 = wsrc4(wc, wb, wm_, d - 1, nq);
            v = cw1 * w0 + cw2 * wn1;
            if (d + 1 < D_IN_) v += cw0 * wsrc4(wc, wb, wm_, d + 1, nq);
        }
        u32x2 p; p.x = pack2(v.x, v.y); p.y = pack2(v.z, v.w);
        *(u32x2*)&tile[dl * 196 + nq * 4] = p;
    }
    __syncthreads();
    for (int i = 0; i < 6; ++i) {
        int idx = tid + i * 256;                // 192 n x 8 chunks
        int n = idx >> 3, ch = idx & 7;
        short8 o;
        for (int j = 0; j < 8; ++j) o[j] = (short)tile[(ch * 8 + j) * 196 + n];
        *(short8*)(wbt + (long)n * KROWS + r0 + ch * 8) = o;
    }
}

// C[j] = bias + ctx @ W'[0:256, j] (+ conv_b * colsum, generally zero); ctx fused in
__global__ void k_cvec(const int* genre, const int* tempo, const int* keysig,
                       const float* emb,
                       const float* wc, const float* wb, const float* wm_,
                       const float* conv_w, const float* conv_b,
                       const float* bc, const float* bb, const float* bm_, float* C) {
    int j = blockIdx.x;          // 0..167
    int lane = threadIdx.x;      // 64
    int g = genre[0], tt = tempo[0], kk = keysig[0];
    float cw0 = conv_w[3], cw1 = conv_w[4], cw2 = conv_w[5];
    float s = 0.f;
    for (int d = lane; d < 256; d += 64) {
        float cx = emb[g * 256 + d] + emb[(10 + tt) * 256 + d] +
                   emb[(20 + kk) * 256 + d] + emb[34 * 256 + d];
        float wp = cw1 * wsrc(wc, wb, wm_, d, j) + cw0 * wsrc(wc, wb, wm_, d + 1, j);
        if (d > 0) wp += cw2 * wsrc(wc, wb, wm_, d - 1, j);
        s += cx * wp;
    }
    float cb = conv_b[0];
    if (cb != 0.f) {
        float cs = 0.f;
        for (int d = lane; d < D_IN_; d += 64) cs += wsrc(wc, wb, wm_, d, j);
        s += cb * cs;
    }
    for (int off = 32; off; off >>= 1) s += __shfl_down(s, off);
    if (lane == 0) {
        float b = (j < NCH) ? bc[j] : (j < NCH + NBE) ? bb[j - NCH] : bm_[j - NCH - NBE];
        C[j] = s + b;
    }
}

// Split-K GEMM — single-buffered 2-barrier phase (m97 pattern), max occupancy:
//  - tile 32 rows x 192 cols x 64 K; 512 thr = 8 waves = 2M x 4N.
//  - A (4 KB bf16) and B (24 KB bf16) both staged in LDS; 28 KB total ->
//    4 blocks/CU (wave-capped) when VGPR <= 64.
//  - phase: issue global loads(t+1) -> regs; compute(t) from LDS; barrier;
//    pack+write(t+1) to LDS; barrier.  Scalar regsets only (no spill bait).
__global__ __launch_bounds__(512, 4) void k_gemm(const float* mel, const float* lyr,
                                                 const unsigned short* wbt,
                                                 float* partial) {
    __shared__ unsigned short Bs[NPAD * 64];       // 24 KB, [n][k] swizzled
    __shared__ unsigned short As[32 * 64];         // 4 KB,  [row][k] swizzled
    const int blk = blockIdx.x;
    const int ks = ((blk & 7) << 1) | ((blk >> 3) & 1);  // XCD x -> ks {2x,2x+1}
    const int bm = blk >> 4;                             // 0..63 (32-row tiles)
    const int tid = threadIdx.x, lane = tid & 63, wv = tid >> 6;
    const int wm = wv >> 2, wn = wv & 3;                 // 2 M-groups x 4 N-groups
    const int l15 = lane & 15, lk = lane >> 4;
    const int start = ks * 49 + (ks < 8 ? ks : 8);
    const int cnt = 49 + (ks < 8 ? 1 : 0);

    // A-stage coords: thread -> (row, 4-col group); one f32x4 per thread per tile
    const int sar = tid >> 4, sac = tid & 15;
    const long sabase = (long)(bm * 32 + sar);
    // B-stage coords: 3 x short8 per thread
    const int bn = tid >> 3, bch = tid & 7;

    f32x4 acc[3];
    #pragma unroll
    for (int i = 0; i < 3; ++i) acc[i] = (f32x4){0.f, 0.f, 0.f, 0.f};

    auto loadAstage = [&](int t2, f32x4& v) {
        int gt = start + t2;
        int r0 = gt * 64;
        if (r0 < 256) {                        // whole tile in melody (tiles 0..3)
            v = *(const f32x4u*)(mel + sabase * 256 + r0 + sac * 4);
        } else if (gt != TOTSTEP - 1) {        // uniform lyrics fast path
            v = *(const f32x4u*)(lyr + sabase * D_LYR_ + (r0 - 256) + sac * 4);
        } else {                               // tail tile: per-element guard
            int c = r0 - 256 + sac * 4;
            const float* p = lyr + sabase * D_LYR_ + c;
            #pragma unroll
            for (int q = 0; q < 4; ++q) v[q] = (c + q < D_LYR_) ? p[q] : 0.f;
        }
    };
    auto writeA = [&](const f32x4& v) {
        u32x2 pk; pk.x = pack2(v.x, v.y); pk.y = pack2(v.z, v.w);
        *(u32x2*)((char*)As + sar * 128 + ((sac * 8) ^ ((sar & 7) << 4))) = pk;
    };
    auto loadBreg = [&](int t2, short8* brg) {
        int r0 = (start + t2) * 64;
        #pragma unroll
        for (int i = 0; i < 3; ++i) {
            int n = bn + i * 64;
            brg[i] = *(const short8*)(wbt + (long)n * KROWS + r0 + bch * 8);
        }
    };
    auto writeB = [&](const short8* brg) {
        #pragma unroll
        for (int i = 0; i < 3; ++i) {
            int n = bn + i * 64;
            *(short8*)((char*)Bs + n * 128 + ((bch * 16) ^ ((n & 7) << 4))) = brg[i];
        }
    };

    auto compute = [&]() {
        #pragma unroll
        for (int kk = 0; kk < 2; ++kk) {
            int ar = wm * 16 + l15;
            short8 af = *(const short8*)((char*)As + ar * 128 +
                                         (((kk * 64) + lk * 16) ^ ((ar & 7) << 4)));
            #pragma unroll
            for (int ni = 0; ni < 3; ++ni) {
                int n = wn * 48 + ni * 16 + l15;
                short8 bf = *(const short8*)((char*)Bs + n * 128 +
                                             (((kk * 64) + lk * 16) ^ ((n & 7) << 4)));
                acc[ni] = __builtin_amdgcn_mfma_f32_16x16x32_bf16(af, bf, acc[ni], 0, 0, 0);
            }
        }
    };

    // prologue: stage tile 0
    {
        f32x4 av; short8 bvr[3];
        loadAstage(0, av); loadBreg(0, bvr);
        writeA(av); writeB(bvr);
    }
    __syncthreads();

    for (int t = 0;;) {
        bool pf = (t + 1 < cnt);
        f32x4 av; short8 bvr[3];
        if (pf) { loadAstage(t + 1, av); loadBreg(t + 1, bvr); }  // in flight over compute
        compute();
        if (!pf) break;
        __syncthreads();             // all reads of current tile retired
        writeA(av); writeB(bvr);
        __syncthreads();             // staged tile visible
        ++t;
    }

    // deterministic partial store
    float* pbase = partial + (long)ks * PARTN;
    int rb = bm * 32 + wm * 16 + lk * 4;
    #pragma unroll
    for (int ni = 0; ni < 3; ++ni) {
        int col = wn * 48 + ni * 16 + l15;
        if (col < NOUT) {
            #pragma unroll
            for (int q = 0; q < 4; ++q)
                pbase[(long)(rb + q) * NOUT + col] = acc[ni][q];
        }
    }
}

__global__ void k_reduce(const float* partial, const float* C, float* out) {
    int idx = blockIdx.x * 256 + threadIdx.x;    // vec4 index
    if (idx >= PARTN / 4) return;
    int base = idx * 4;
    f32x4 s;
    for (int q = 0; q < 4; ++q) s[q] = C[(base + q) % NOUT];
    for (int ks = 0; ks < KSPLIT; ++ks)
        s += *(const f32x4*)(partial + (long)ks * PARTN + base);
    *(f32x4*)(out + base) = s;
}

extern "C" void kernel_launch(void* const* d_in, const int* in_sizes, int n_in,
                              void* d_out, int out_size, void* d_ws, size_t ws_size,
                              hipStream_t stream) {
    const int*   genre   = (const int*)d_in[0];
    const int*   tempo   = (const int*)d_in[1];
    const int*   keysig  = (const int*)d_in[2];
    const float* mel     = (const float*)d_in[4];
    const float* lyr     = (const float*)d_in[5];
    const float* emb     = (const float*)d_in[6];
    const float* conv_w  = (const float*)d_in[7];
    const float* conv_b  = (const float*)d_in[8];
    const float* w_chord = (const float*)d_in[9];
    const float* b_chord = (const float*)d_in[10];
    const float* w_beat  = (const float*)d_in[11];
    const float* b_beat  = (const float*)d_in[12];
    const float* w_mel   = (const float*)d_in[13];
    const float* b_mel   = (const float*)d_in[14];

    char* ws = (char*)d_ws;
    unsigned short* wbt = (unsigned short*)ws;              // 192*50688*2 = 19,464,192 B
    float* Cvec    = (float*)(ws + 19464192);               // 1 KB
    float* partial = (float*)(ws + 19466240);               // 16*344064*4 = 22,020,096 B
    float* out     = (float*)d_out;

    hipLaunchKernelGGL(k_fold, dim3(TOTSTEP), dim3(256), 0, stream,
                       w_chord, w_beat, w_mel, conv_w, wbt);
    hipLaunchKernelGGL(k_cvec, dim3(NOUT), dim3(64), 0, stream,
                       genre, tempo, keysig, emb,
                       w_chord, w_beat, w_mel, conv_w, conv_b,
                       b_chord, b_beat, b_mel, Cvec);
    hipLaunchKernelGGL(k_gemm, dim3(1024), dim3(512), 0, stream,
                       mel, lyr, wbt, partial);
    hipLaunchKernelGGL(k_reduce, dim3((PARTN / 4 + 255) / 256), dim3(256), 0, stream,
                       partial, Cvec, out);
}

// Round 9
// 204.333 us; speedup vs baseline: 2.2359x; 1.0949x over previous
//
#include <hip/hip_runtime.h>

#define D_IN_   50937
#define D_LYR_  50425
#define NCH     24
#define NBE     16
#define NME     128
#define NOUT    168
#define NPAD    192
#define KROWS   50688        // padded GEMM K: 256 melody + 50432 lyrics (mult of 64)
#define KSPLIT  16
#define TOTSTEP 792          // KROWS/64
#define PARTN   (2048*168)   // 344064

typedef __attribute__((ext_vector_type(8))) short short8;
typedef __attribute__((ext_vector_type(4))) float f32x4;
typedef float f32x4u __attribute__((ext_vector_type(4), aligned(4)));
typedef __attribute__((ext_vector_type(2))) unsigned int u32x2;

static __device__ __forceinline__ unsigned short f2bf(float f) {
    unsigned int u = __float_as_uint(f);
    u += 0x7FFF + ((u >> 16) & 1);          // round-to-nearest-even
    return (unsigned short)(u >> 16);
}
static __device__ __forceinline__ unsigned int pack2(float x, float y) {
    return (unsigned int)f2bf(x) | ((unsigned int)f2bf(y) << 16);
}

// scalar W[d][n] over concatenated heads
static __device__ __forceinline__ float wsrc(const float* wc, const float* wb,
                                             const float* wm, int d, int n) {
    if (n < NCH)        return wc[d * NCH + n];
    if (n < NCH + NBE)  return wb[d * NBE + (n - NCH)];
    if (n < NOUT)       return wm[(long)d * NME + (n - NCH - NBE)];
    return 0.f;
}
// quad W[d][n0..n0+3]; head boundaries (24,40,168) are 4-aligned so quads never straddle
static __device__ __forceinline__ f32x4 wsrc4(const float* wc, const float* wb,
                                              const float* wm, int d, int nq) {
    int n0 = nq * 4;
    if (n0 < 24)  return *(const f32x4*)(wc + d * 24 + n0);
    if (n0 < 40)  return *(const f32x4*)(wb + d * 16 + (n0 - 24));
    if (n0 < 168) return *(const f32x4*)(wm + (long)d * 128 + (n0 - 40));
    f32x4 z = {0.f, 0.f, 0.f, 0.f};
    return z;
}

// folded, transposed, bf16 weights: wbt[n][r], r = d-256
__global__ __launch_bounds__(256) void k_fold(const float* wc, const float* wb,
                                              const float* wm_, const float* conv_w,
                                              unsigned short* wbt) {
    __shared__ unsigned short tile[64 * 196];   // [dloc][n], pad 196 (8B-aligned rows)
    float cw0 = conv_w[3], cw1 = conv_w[4], cw2 = conv_w[5];
    int r0 = blockIdx.x * 64;
    int tid = threadIdx.x;
    for (int i = 0; i < 12; ++i) {
        int idx = tid + i * 256;                // 64 rows x 48 quads
        int dl = idx / 48, nq = idx % 48;
        int r = r0 + dl;
        f32x4 v = {0.f, 0.f, 0.f, 0.f};
        if (r < 50681) {                        // rows >= 50681 stay zero (pads A-tail)
            int d = 256 + r;
            f32x4 w0 = wsrc4(wc, wb, wm_, d, nq);
            f32x4 wn1 = wsrc4(wc, wb, wm_, d - 1, nq);
            v = cw1 * w0 + cw2 * wn1;
            if (d + 1 < D_IN_) v += cw0 * wsrc4(wc, wb, wm_, d + 1, nq);
        }
        u32x2 p; p.x = pack2(v.x, v.y); p.y = pack2(v.z, v.w);
        *(u32x2*)&tile[dl * 196 + nq * 4] = p;
    }
    __syncthreads();
    for (int i = 0; i < 6; ++i) {
        int idx = tid + i * 256;                // 192 n x 8 chunks
        int n = idx >> 3, ch = idx & 7;
        short8 o;
        for (int j = 0; j < 8; ++j) o[j] = (short)tile[(ch * 8 + j) * 196 + n];
        *(short8*)(wbt + (long)n * KROWS + r0 + ch * 8) = o;
    }
}

// C[j] = bias + ctx @ W'[0:256, j] (+ conv_b * colsum, generally zero); ctx fused in
__global__ void k_cvec(const int* genre, const int* tempo, const int* keysig,
                       const float* emb,
                       const float* wc, const float* wb, const float* wm_,
                       const float* conv_w, const float* conv_b,
                       const float* bc, const float* bb, const float* bm_, float* C) {
    int j = blockIdx.x;          // 0..167
    int lane = threadIdx.x;      // 64
    int g = genre[0], tt = tempo[0], kk = keysig[0];
    float cw0 = conv_w[3], cw1 = conv_w[4], cw2 = conv_w[5];
    float s = 0.f;
    for (int d = lane; d < 256; d += 64) {
        float cx = emb[g * 256 + d] + emb[(10 + tt) * 256 + d] +
                   emb[(20 + kk) * 256 + d] + emb[34 * 256 + d];
        float wp = cw1 * wsrc(wc, wb, wm_, d, j) + cw0 * wsrc(wc, wb, wm_, d + 1, j);
        if (d > 0) wp += cw2 * wsrc(wc, wb, wm_, d - 1, j);
        s += cx * wp;
    }
    float cb = conv_b[0];
    if (cb != 0.f) {
        float cs = 0.f;
        for (int d = lane; d < D_IN_; d += 64) cs += wsrc(wc, wb, wm_, d, j);
        s += cb * cs;
    }
    for (int off = 32; off; off >>= 1) s += __shfl_down(s, off);
    if (lane == 0) {
        float b = (j < NCH) ? bc[j] : (j < NCH + NBE) ? bb[j - NCH] : bm_[j - NCH - NBE];
        C[j] = s + b;
    }
}

// Split-K GEMM — R2 skeleton with doubled per-wave work (latency-bound fix):
//  - tile 64 rows x 192 cols x 64 K; 256 thr = 4 waves = 2M x 2N;
//    wave = 32 rows x 96 cols = 2 A-frags x 6 B-frags = 24 MFMA/phase,
//    16 outstanding dwordx4 A-loads/phase (deep per-wave ILP).
//  - A: global->reg ping-pong (2 named regsets, R2-proven; NO 3-set spill bait).
//  - B: reg-staged double-buffered LDS (48 KB), ONE __syncthreads per phase:
//    phase t: issue A(t+1)+B(t+1) loads; compute(t) from buf t&1; write B(t+1)
//    to buf ~t&1; barrier.
//  - grid 512 = 32 mb x 16 ks (XCD-pinned ks) = 2 blocks/CU for phase skew.
__global__ __launch_bounds__(256, 2) void k_gemm(const float* mel, const float* lyr,
                                                 const unsigned short* wbt,
                                                 float* partial) {
    __shared__ unsigned short Bs[2 * NPAD * 64];   // 2 x 24 KB
    const int blk = blockIdx.x;
    const int ks = ((blk & 7) << 1) | ((blk >> 3) & 1);  // XCD x -> ks {2x,2x+1}
    const int bm = blk >> 4;                             // 0..31 (64-row tiles)
    const int tid = threadIdx.x, lane = tid & 63, wv = tid >> 6;
    const int wm = wv >> 1, wn = wv & 1;                 // 2 M-groups x 2 N-groups
    const int l15 = lane & 15, lk = lane >> 4;
    const int start = ks * 49 + (ks < 8 ? ks : 8);
    const int cnt = 49 + (ks < 8 ? 1 : 0);

    // per-wave A row bases: 2 frags (mi=0,1), rows bm*64 + wm*32 + mi*16 + l15
    const float* melB0 = mel + (bm * 64 + wm * 32 + l15) * 256;
    const float* melB1 = melB0 + 16 * 256;
    const float* lyrB0 = lyr + (long)(bm * 64 + wm * 32 + l15) * D_LYR_ - 256;
    const float* lyrB1 = lyrB0 + 16L * D_LYR_;

    // B-stage coords: 6 x short8 per thread (192 rows / 32 row-groups)
    const int bn = tid >> 3, bch = tid & 7;

    f32x4 acc[2][6];
    #pragma unroll
    for (int mi = 0; mi < 2; ++mi)
        #pragma unroll
        for (int ni = 0; ni < 6; ++ni) acc[mi][ni] = (f32x4){0.f, 0.f, 0.f, 0.f};

    auto loadA = [&](int t2, f32x4* dst) {   // dst[8] = [mi*4 + kk*2 + half]
        int gt = start + t2;
        int r0 = gt * 64;
        if (gt != TOTSTEP - 1) {             // uniform fast path
            #pragma unroll
            for (int kk = 0; kk < 2; ++kk) {
                int r = r0 + kk * 32 + lk * 8;
                const float* p0 = (r < 256) ? (melB0 + r) : (lyrB0 + r);
                const float* p1 = (r < 256) ? (melB1 + r) : (lyrB1 + r);
                dst[kk * 2]     = *(const f32x4u*)p0;
                dst[kk * 2 + 1] = *(const f32x4u*)(p0 + 4);
                dst[4 + kk * 2]     = *(const f32x4u*)p1;
                dst[4 + kk * 2 + 1] = *(const f32x4u*)(p1 + 4);
            }
        } else {                             // tail tile (block-uniform branch)
            #pragma unroll
            for (int kk = 0; kk < 2; ++kk) {
                int r = r0 + kk * 32 + lk * 8;
                int c = r - 256;
                const float* p0 = lyrB0 + r;
                const float* p1 = lyrB1 + r;
                f32x4 a0, a1, b0, b1;
                #pragma unroll
                for (int q = 0; q < 4; ++q) {
                    a0[q] = (c + q     < D_LYR_) ? p0[q]     : 0.f;
                    a1[q] = (c + 4 + q < D_LYR_) ? p0[4 + q] : 0.f;
                    b0[q] = (c + q     < D_LYR_) ? p1[q]     : 0.f;
                    b1[q] = (c + 4 + q < D_LYR_) ? p1[4 + q] : 0.f;
                }
                dst[kk * 2] = a0; dst[kk * 2 + 1] = a1;
                dst[4 + kk * 2] = b0; dst[4 + kk * 2 + 1] = b1;
            }
        }
    };

    auto loadBreg = [&](int t2, short8* brg) {   // 6 x 16B per thread, L2-resident
        int r0 = (start + t2) * 64;
        #pragma unroll
        for (int i = 0; i < 6; ++i) {
            int n = bn + i * 32;
            brg[i] = *(const short8*)(wbt + (long)n * KROWS + r0 + bch * 8);
        }
    };
    auto writeB = [&](const short8* brg, int buf) {
        char* Bb = (char*)Bs + buf * 24576;
        #pragma unroll
        for (int i = 0; i < 6; ++i) {
            int n = bn + i * 32;
            *(short8*)(Bb + n * 128 + ((bch * 16) ^ ((n & 7) << 4))) = brg[i];
        }
    };

    auto compute = [&](const f32x4* a, int buf) {
        const char* Bb = (const char*)Bs + buf * 24576;
        #pragma unroll
        for (int kk = 0; kk < 2; ++kk) {
            short8 af[2];
            #pragma unroll
            for (int mi = 0; mi < 2; ++mi) {
                f32x4 v0 = a[mi * 4 + kk * 2], v1 = a[mi * 4 + kk * 2 + 1];
                short8 o;
                o[0] = (short)f2bf(v0.x); o[1] = (short)f2bf(v0.y);
                o[2] = (short)f2bf(v0.z); o[3] = (short)f2bf(v0.w);
                o[4] = (short)f2bf(v1.x); o[5] = (short)f2bf(v1.y);
                o[6] = (short)f2bf(v1.z); o[7] = (short)f2bf(v1.w);
                af[mi] = o;
            }
            #pragma unroll
            for (int ni = 0; ni < 6; ++ni) {
                int n = wn * 96 + ni * 16 + l15;
                int byte = n * 128 + (((kk * 64) + lk * 16) ^ ((n & 7) << 4));
                short8 bf = *(const short8*)(Bb + byte);
                #pragma unroll
                for (int mi = 0; mi < 2; ++mi)
                    acc[mi][ni] = __builtin_amdgcn_mfma_f32_16x16x32_bf16(
                        af[mi], bf, acc[mi][ni], 0, 0, 0);
            }
        }
    };

    f32x4 rgA[8], rgB[8];
    // prologue: A(0) issued; B(0) staged into buf 0
    loadA(0, rgA);
    {
        short8 b0[6];
        loadBreg(0, b0);
        writeB(b0, 0);
    }
    __syncthreads();

    for (int t = 0;;) {
        {   // even phase: compute rgA from buf t&1
            bool pf = (t + 1 < cnt);
            short8 brg[6];
            if (pf) { loadA(t + 1, rgB); loadBreg(t + 1, brg); }
            compute(rgA, t & 1);
            if (!pf) break;
            writeB(brg, (t + 1) & 1);
            __syncthreads();
            ++t;
        }
        {   // odd phase: compute rgB
            bool pf = (t + 1 < cnt);
            short8 brg[6];
            if (pf) { loadA(t + 1, rgA); loadBreg(t + 1, brg); }
            compute(rgB, t & 1);
            if (!pf) break;
            writeB(brg, (t + 1) & 1);
            __syncthreads();
            ++t;
        }
    }

    // deterministic partial store
    float* pbase = partial + (long)ks * PARTN;
    #pragma unroll
    for (int mi = 0; mi < 2; ++mi) {
        int rb = bm * 64 + wm * 32 + mi * 16 + lk * 4;
        #pragma unroll
        for (int ni = 0; ni < 6; ++ni) {
            int col = wn * 96 + ni * 16 + l15;
            if (col < NOUT) {
                #pragma unroll
                for (int q = 0; q < 4; ++q)
                    pbase[(long)(rb + q) * NOUT + col] = acc[mi][ni][q];
            }
        }
    }
}

__global__ void k_reduce(const float* partial, const float* C, float* out) {
    int idx = blockIdx.x * 256 + threadIdx.x;    // vec4 index
    if (idx >= PARTN / 4) return;
    int base = idx * 4;
    f32x4 s;
    for (int q = 0; q < 4; ++q) s[q] = C[(base + q) % NOUT];
    for (int ks = 0; ks < KSPLIT; ++ks)
        s += *(const f32x4*)(partial + (long)ks * PARTN + base);
    *(f32x4*)(out + base) = s;
}

extern "C" void kernel_launch(void* const* d_in, const int* in_sizes, int n_in,
                              void* d_out, int out_size, void* d_ws, size_t ws_size,
                              hipStream_t stream) {
    const int*   genre   = (const int*)d_in[0];
    const int*   tempo   = (const int*)d_in[1];
    const int*   keysig  = (const int*)d_in[2];
    const float* mel     = (const float*)d_in[4];
    const float* lyr     = (const float*)d_in[5];
    const float* emb     = (const float*)d_in[6];
    const float* conv_w  = (const float*)d_in[7];
    const float* conv_b  = (const float*)d_in[8];
    const float* w_chord = (const float*)d_in[9];
    const float* b_chord = (const float*)d_in[10];
    const float* w_beat  = (const float*)d_in[11];
    const float* b_beat  = (const float*)d_in[12];
    const float* w_mel   = (const float*)d_in[13];
    const float* b_mel   = (const float*)d_in[14];

    char* ws = (char*)d_ws;
    unsigned short* wbt = (unsigned short*)ws;              // 192*50688*2 = 19,464,192 B
    float* Cvec    = (float*)(ws + 19464192);               // 1 KB
    float* partial = (float*)(ws + 19466240);               // 16*344064*4 = 22,020,096 B
    float* out     = (float*)d_out;

    hipLaunchKernelGGL(k_fold, dim3(TOTSTEP), dim3(256), 0, stream,
                       w_chord, w_beat, w_mel, conv_w, wbt);
    hipLaunchKernelGGL(k_cvec, dim3(NOUT), dim3(64), 0, stream,
                       genre, tempo, keysig, emb,
                       w_chord, w_beat, w_mel, conv_w, conv_b,
                       b_chord, b_beat, b_mel, Cvec);
    hipLaunchKernelGGL(k_gemm, dim3(512), dim3(256), 0, stream,
                       mel, lyr, wbt, partial);
    hipLaunchKernelGGL(k_reduce, dim3((PARTN / 4 + 255) / 256), dim3(256), 0, stream,
                       partial, Cvec, out);
}